// Round 5
// baseline (112.460 us; speedup 1.0000x reference)
//
#include <hip/hip_runtime.h>
#include <hip/hip_bf16.h>
#include <hip/hip_fp8.h>

// Problem constants (fixed by reference): N=4096, D=256, T=0.5, EPS=1e-8
#define PN   4096
#define PN2  8192
#define PD   256                       // also row stride in BYTES for fp8 zn
#define TILE 128
#define BK   128                       // fp8 k-elems per slab = 128 B/row
#define NBLK (PN2 / TILE)              // 64 tile-blocks per dim
#define NTRI (NBLK * (NBLK + 1) / 2)   // 2080 upper-tri blocks (2080 % 8 == 0)

typedef __attribute__((ext_vector_type(4))) float f32x4;
typedef const __attribute__((address_space(1))) void* gas_ptr;
typedef __attribute__((address_space(3))) void* las_ptr;

// ---------------------------------------------------------------------------
// Kernel 1: pair-wise normalize. One WAVE per pair (r, r+N): loads zi_r, zj_r
// (fp32), computes |zi|, |zj|, dot -> pos[r]=pos[r+N] in FULL FP32 (positives
// never touch fp8), writes both rows of zn as OCP e4m3 (2 MiB total).
// ---------------------------------------------------------------------------
__global__ __launch_bounds__(256) void normalize_kernel(
    const float* __restrict__ zi, const float* __restrict__ zj,
    unsigned char* __restrict__ zn8, float* __restrict__ pos,
    float* __restrict__ wlws, unsigned* __restrict__ ticket) {
  const int wave = threadIdx.x >> 6;
  const int lane = threadIdx.x & 63;
  const int r = blockIdx.x * 4 + wave;           // pair id 0..4095
  float4 a = *(const float4*)(zi + (size_t)r * PD + lane * 4);  // 16B/lane
  float4 b = *(const float4*)(zj + (size_t)r * PD + lane * 4);
  float si = a.x * a.x + a.y * a.y + a.z * a.z + a.w * a.w;
  float sj = b.x * b.x + b.y * b.y + b.z * b.z + b.w * b.w;
  float d  = a.x * b.x + a.y * b.y + a.z * b.z + a.w * b.w;
  #pragma unroll
  for (int off = 32; off >= 1; off >>= 1) {
    si += __shfl_xor(si, off, 64);
    sj += __shfl_xor(sj, off, 64);
    d  += __shfl_xor(d,  off, 64);
  }
  float ni = fmaxf(sqrtf(si), 1e-8f);
  float nj = fmaxf(sqrtf(sj), 1e-8f);
  if (lane == 0) {                     // exact fp32 positives (and mirror)
    float p = d / (ni * nj);
    pos[r] = p;
    pos[r + PN] = p;
  }
  float ia = 1.0f / ni, ib = 1.0f / nj;
  union { unsigned u; unsigned char c[4]; } pa, pb;
  pa.c[0] = __hip_cvt_float_to_fp8(a.x * ia, __HIP_SATFINITE, __HIP_E4M3);
  pa.c[1] = __hip_cvt_float_to_fp8(a.y * ia, __HIP_SATFINITE, __HIP_E4M3);
  pa.c[2] = __hip_cvt_float_to_fp8(a.z * ia, __HIP_SATFINITE, __HIP_E4M3);
  pa.c[3] = __hip_cvt_float_to_fp8(a.w * ia, __HIP_SATFINITE, __HIP_E4M3);
  pb.c[0] = __hip_cvt_float_to_fp8(b.x * ib, __HIP_SATFINITE, __HIP_E4M3);
  pb.c[1] = __hip_cvt_float_to_fp8(b.y * ib, __HIP_SATFINITE, __HIP_E4M3);
  pb.c[2] = __hip_cvt_float_to_fp8(b.z * ib, __HIP_SATFINITE, __HIP_E4M3);
  pb.c[3] = __hip_cvt_float_to_fp8(b.w * ib, __HIP_SATFINITE, __HIP_E4M3);
  *(unsigned*)(zn8 + (size_t)r * PD + lane * 4) = pa.u;          // 4B/lane
  *(unsigned*)(zn8 + (size_t)(r + PN) * PD + lane * 4) = pb.u;
  if (blockIdx.x == 0 && threadIdx.x == 0) {     // ws poisoned 0xAA pre-launch
    wlws[0] = 0.0f; wlws[1] = 0.0f; *ticket = 0u;
  }
}

// ---------------------------------------------------------------------------
// Kernel 2: sim = zn @ zn^T in FP8 e4m3, UPPER-TRIANGULAR blocks (symmetry).
// EXACT round-0 structure/geometry (proven 43.8us at bf16): TILE=128, 4 waves,
// 32 KiB single-buffer LDS (multi-block/CU MLP preserved), 2-barrier kt-loop,
// 128B rows with 16B-granule XOR swizzle (both-sides, rule #21). fp8 halves
// staged bytes (266 -> 133 MB) and zn (2 MiB) now fits each XCD L2 with room.
// kt: 2 slabs of BK=128; ki: 4 x mfma_f32_16x16x32_fp8_fp8 per slab.
// Epilogue: LDS accumulation, unique-writer plain stores into rowpart.
// ---------------------------------------------------------------------------
__global__ __launch_bounds__(256) void simsum_kernel(
    const unsigned char* __restrict__ zn8, float* __restrict__ rowpart) {
  __shared__ char lds[2 * TILE * BK];   // 32 KiB: As then Bs
  __shared__ float rowacc[TILE];
  __shared__ float colacc[TILE];
  char* As = lds;
  char* Bs = lds + TILE * BK;

  const int tid = threadIdx.x;
  if (tid < TILE) { rowacc[tid] = 0.0f; colacc[tid] = 0.0f; }

  // XCD swizzle (bijective, 2080 % 8 == 0): consecutive idx share bj panel
  const int idx = (int)((blockIdx.x & 7) * (NTRI / 8) + (blockIdx.x >> 3));
  // Decode upper-tri (bi<=bj): idx = T(bj) + bi, T(bj)=bj(bj+1)/2
  int bj = (int)((sqrtf(8.0f * (float)idx + 1.0f) - 1.0f) * 0.5f);
  while ((bj + 1) * (bj + 2) / 2 <= idx) ++bj;
  while (bj * (bj + 1) / 2 > idx) --bj;
  const int bi = idx - bj * (bj + 1) / 2;
  const bool diagBlk = (bi == bj);

  const int wave = tid >> 6;
  const int lane = tid & 63;
  const int quad = lane >> 4;
  const int c16  = lane & 15;
  const int rowBase = bi * TILE;
  const int colBase = bj * TILE;
  const int waveRow = (wave >> 1) * 64;
  const int waveCol = (wave & 1) * 64;
  const int subrow = lane >> 3;  // 0..7 (row within an 8-row issue)
  const int slot   = lane & 7;   // 0..7 (16B granule within a 128B LDS row)

  f32x4 acc[4][4];
  #pragma unroll
  for (int i = 0; i < 4; ++i)
    #pragma unroll
    for (int j = 0; j < 4; ++j)
      acc[i][j] = (f32x4){0.f, 0.f, 0.f, 0.f};

  const char* BsEff = diagBlk ? As : Bs;

  for (int kt = 0; kt < PD / BK; ++kt) {         // 2 kt steps
    if (kt) __syncthreads();     // protect LDS before overwrite
    // Stage A (and B if off-diag): 16 issues x 1 KiB (8 rows x 128B), source
    // pre-swizzled so LDS granule g of row rr holds global granule g^(rr&7).
    #pragma unroll
    for (int p = 0; p < 4; ++p) {
      int issue = wave * 4 + p;            // 0..15, wave-uniform
      int rr = issue * 8 + subrow;         // tile row 0..127
      int cc = slot ^ (rr & 7);            // swizzled 16B-granule
      const unsigned char* ga = zn8 + (size_t)(rowBase + rr) * PD + kt * BK + cc * 16;
      __builtin_amdgcn_global_load_lds((gas_ptr)ga, (las_ptr)(As + issue * 1024), 16, 0, 0);
      if (!diagBlk) {
        const unsigned char* gb = zn8 + (size_t)(colBase + rr) * PD + kt * BK + cc * 16;
        __builtin_amdgcn_global_load_lds((gas_ptr)gb, (las_ptr)(Bs + issue * 1024), 16, 0, 0);
      }
    }
    __syncthreads();             // s_waitcnt vmcnt(0) before s_barrier

    #pragma unroll
    for (int ki = 0; ki < 4; ++ki) {       // four k=32 fp8 MFMA steps per slab
      // lane's 8 fp8: k = ki*32 + quad*8 + j  ->  global granule G, half h
      const int G  = ki * 2 + (quad >> 1);
      const int h8 = (quad & 1) * 8;
      long a[4], b[4];
      #pragma unroll
      for (int mi = 0; mi < 4; ++mi) {
        int r = waveRow + mi * 16 + c16;   // A row: m = lane&15
        a[mi] = *(const long*)(As + r * 128 + (((G ^ (r & 7)) << 4) + h8));
      }
      #pragma unroll
      for (int ni = 0; ni < 4; ++ni) {
        int r = waveCol + ni * 16 + c16;   // B "row" of zn = sim column n
        b[ni] = *(const long*)(BsEff + r * 128 + (((G ^ (r & 7)) << 4) + h8));
      }
      #pragma unroll
      for (int mi = 0; mi < 4; ++mi)
        #pragma unroll
        for (int ni = 0; ni < 4; ++ni)
          acc[mi][ni] = __builtin_amdgcn_mfma_f32_16x16x32_fp8_fp8(a[mi], b[ni], acc[mi][ni], 0, 0, 0);
    }
  }

  // Epilogue. C/D layout: col=lane&15, row=quad*4+reg (shape-determined,
  // dtype-independent [m121-m128]). No pos handling (fp32 path in normalize).
  float colsum[4] = {0.f, 0.f, 0.f, 0.f};   // per-ni column partials (off-diag)
  #pragma unroll
  for (int mi = 0; mi < 4; ++mi) {
    int lrow = waveRow + mi * 16 + quad * 4;      // local row 0..127
    float rs[4] = {0.f, 0.f, 0.f, 0.f};
    #pragma unroll
    for (int ni = 0; ni < 4; ++ni) {
      int gcol = colBase + waveCol + ni * 16 + c16;
      #pragma unroll
      for (int t = 0; t < 4; ++t) {
        int grow = rowBase + lrow + t;
        float e = __expf(2.0f * acc[mi][ni][t]);    // exp(sim / T), T=0.5
        if (diagBlk && gcol == grow) e = 0.0f;      // mask diagonal
        rs[t] += e;
        colsum[ni] += e;
      }
    }
    #pragma unroll
    for (int t = 0; t < 4; ++t) {
      #pragma unroll
      for (int off = 1; off <= 8; off <<= 1) rs[t] += __shfl_xor(rs[t], off, 64);
    }
    if (c16 == 0) {                                  // LDS atomics: per-CU, cheap
      #pragma unroll
      for (int t = 0; t < 4; ++t) atomicAdd(&rowacc[lrow + t], rs[t]);
    }
  }
  if (!diagBlk) {   // column contributions = mirrored rows (symmetry)
    #pragma unroll
    for (int ni = 0; ni < 4; ++ni) {
      float cs = colsum[ni];
      cs += __shfl_xor(cs, 16, 64);
      cs += __shfl_xor(cs, 32, 64);
      if (quad == 0) atomicAdd(&colacc[waveCol + ni * 16 + c16], cs);
    }
  }

  __syncthreads();                // all LDS accumulation done
  if (tid < TILE) {               // plain stores, unique writers:
    rowpart[(size_t)bj * PN2 + rowBase + tid] = rowacc[tid];
    if (!diagBlk)
      rowpart[(size_t)bi * PN2 + colBase + tid] = colacc[tid];
  }
}

// ---------------------------------------------------------------------------
// Kernel 3: rowsum[r] = sum_x rowpart[x][r]; loss_r = log(rowsum)-2*pos;
// out = sum(w*loss)/sum(w). 32 blocks x 256 threads, 1 row/thread.
// ---------------------------------------------------------------------------
__global__ __launch_bounds__(256) void finalize_kernel(
    const float* __restrict__ rowpart, const float* __restrict__ pos,
    const float* __restrict__ w, float* __restrict__ wlws,
    unsigned* __restrict__ ticket, float* __restrict__ out) {
  const int tid = threadIdx.x;
  const int r = blockIdx.x * 256 + tid;     // 32*256 = 8192
  float s = 0.0f;
  #pragma unroll
  for (int x = 0; x < NBLK; ++x) s += rowpart[(size_t)x * PN2 + r];
  float li = logf(s) - 2.0f * pos[r];
  float wi = w[r & (PN - 1)];
  float wl = wi * li, ws = wi;
  #pragma unroll
  for (int off = 32; off >= 1; off >>= 1) {
    wl += __shfl_xor(wl, off, 64);
    ws += __shfl_xor(ws, off, 64);
  }
  __shared__ float pl[4], pw[4];
  const int lane = tid & 63, wv = tid >> 6;
  if (lane == 0) { pl[wv] = wl; pw[wv] = ws; }
  __syncthreads();
  if (tid == 0) {
    atomicAdd(&wlws[0], pl[0] + pl[1] + pl[2] + pl[3]);
    atomicAdd(&wlws[1], pw[0] + pw[1] + pw[2] + pw[3]);
    __threadfence();
    if (atomicAdd(ticket, 1u) == 31) {      // last of 32 blocks
      float a = atomicAdd(&wlws[0], 0.0f);  // coherent re-read
      float b = atomicAdd(&wlws[1], 0.0f);
      out[0] = a / b;
    }
  }
}

// ---------------------------------------------------------------------------
extern "C" void kernel_launch(void* const* d_in, const int* in_sizes, int n_in,
                              void* d_out, int out_size, void* d_ws, size_t ws_size,
                              hipStream_t stream) {
  const float* zi = (const float*)d_in[0];
  const float* zj = (const float*)d_in[1];
  const float* w  = (const float*)d_in[2];
  float* out = (float*)d_out;

  // Workspace: zn8 u8[8192*256]=2MiB | rowpart f32[64][8192]=2MiB |
  //            pos f32[8192]=32KiB | wlws f32[2] | ticket u32
  unsigned char* zn8 = (unsigned char*)d_ws;
  float* rowpart = (float*)((char*)d_ws + (size_t)PN2 * PD);
  float* pos     = rowpart + (size_t)NBLK * PN2;
  float* wlws    = pos + PN2;
  unsigned* ticket = (unsigned*)(wlws + 2);

  normalize_kernel<<<PN / 4, 256, 0, stream>>>(zi, zj, zn8, pos, wlws, ticket);
  simsum_kernel<<<NTRI, 256, 0, stream>>>(zn8, rowpart);
  finalize_kernel<<<32, 256, 0, stream>>>(rowpart, pos, w, wlws, ticket, out);
}